// Round 3
// baseline (318.173 us; speedup 1.0000x reference)
//
#include <hip/hip_runtime.h>
#include <hip/hip_cooperative_groups.h>
#include <math.h>

namespace cg = cooperative_groups;

// Problem constants
#define BB 8
#define CC 64
#define HH 256
#define WW 256
#define HP 257                     // output spatial (H+1)
#define NPB (HP * HP)              // 66049 outputs per batch

// Padded channel-sum buffer: rows -3..258 (262), cols stride 264 (left pad 4
// for float4 alignment; >=3 halo each side for the 6x6 stencil).
#define SROWS 262
#define SSTR  264
#define SPIMG (SROWS * SSTR)       // 69168 floats per image

// Workspace layout (floats):
//  [0, 1024)        per-block partials (sum,sumsq) pairs, 512 blocks
//  [OFF_SPAD, +BB*SPIMG) padded channel sum
#define OFF_PART 0
#define OFF_SPAD 4352

#define GRID 512                   // cooperative grid (2 blocks/CU)
#define NTHREADS (GRID * 256)

#define N_INT (BB * 16384)         // interior float4 items (131072)
#define PAD_PER_IMG 908            // pad float4 items per image
#define N_TOT (N_INT + BB * PAD_PER_IMG)

#define EPB 1033                   // output elems per block (64 blocks/batch)

// ---- build combined 6x6 weights: (2x2 avg-pool) ∘ (16-tap 5x5 shift stencil) ----
__device__ __forceinline__ void build_w(const float* __restrict__ cw, float W[6][6]) {
    float T[5][5];
#pragma unroll
    for (int i = 0; i < 5; ++i)
#pragma unroll
        for (int j = 0; j < 5; ++j) T[i][j] = 0.f;
#pragma unroll
    for (int d = 0; d < 5; ++d) { T[0][d] = -cw[d]; T[4][d] = cw[4 - d]; }
    T[1][4] = -cw[5]; T[2][4] = -cw[6]; T[3][4] = -cw[7];
    T[1][0] =  cw[7]; T[2][0] =  cw[6]; T[3][0] =  cw[5];
#pragma unroll
    for (int u = 0; u < 6; ++u)
#pragma unroll
        for (int v = 0; v < 6; ++v) {
            float a = 0.f;
#pragma unroll
            for (int dr = u - 1; dr <= u; ++dr)
#pragma unroll
                for (int dc = v - 1; dc <= v; ++dc)
                    if (dr >= 0 && dr < 5 && dc >= 0 && dc < 5) a += T[dr][dc];
            W[u][v] = 0.25f * a;
        }
}

__global__ __launch_bounds__(256) void k_fused(const float* __restrict__ x,
                                               const float* __restrict__ cw,
                                               const float* __restrict__ cbp,
                                               float* __restrict__ ws,
                                               float* __restrict__ out) {
    cg::grid_group grid = cg::this_grid();
    const int tid = threadIdx.x;
    const int blk = blockIdx.x;
    const int gtid = blk * 256 + tid;

    // ---------------- Phase 1: channel sum into padded buffer ----------------
    float4* sp4 = reinterpret_cast<float4*>(ws + OFF_SPAD);
    for (int idx = gtid; idx < N_TOT; idx += NTHREADS) {
        if (idx < N_INT) {
            int b = idx >> 14;                  // 16384 float4 per image
            int p = idx & 16383;
            int i = p >> 6;                     // row 0..255
            int j4 = p & 63;
            const float4* xp = reinterpret_cast<const float4*>(x)
                               + (size_t)b * (CC * 16384) + p;
            float4 acc = make_float4(0.f, 0.f, 0.f, 0.f);
#pragma unroll 16
            for (int c = 0; c < CC; ++c) {
                float4 v = xp[(size_t)c * 16384];
                acc.x += v.x; acc.y += v.y; acc.z += v.z; acc.w += v.w;
            }
            sp4[b * (SPIMG / 4) + (i + 3) * (SSTR / 4) + 1 + j4] = acc;
        } else {
            int j = idx - N_INT;
            int img = j / PAD_PER_IMG;
            int k = j % PAD_PER_IMG;
            int row, col4;
            if (k < 396) {                      // 3 top + 3 bottom full rows
                int r = k / 66;
                row = (r < 3) ? r : 256 + r;    // 0,1,2 / 259,260,261
                col4 = k % 66;
            } else {                            // side pads, rows 3..258
                int k2 = k - 396;
                row = 3 + (k2 >> 1);
                col4 = (k2 & 1) ? 65 : 0;
            }
            sp4[img * (SPIMG / 4) + row * (SSTR / 4) + col4] =
                make_float4(0.f, 0.f, 0.f, 0.f);
        }
    }

    grid.sync();

    // ---------------- Phase 2: stencil -> y (registers) + block partials ----
    const int bb = blk >> 6;                    // batch of this block
    const int sub = blk & 63;
    const int e_base = sub * EPB;
    const int e_end = (e_base + EPB < NPB) ? e_base + EPB : NPB;

    float W[6][6];
    build_w(cw, W);
    const float cb = cbp[0];
    const float* sbase = ws + OFF_SPAD + bb * SPIMG;

    float yv[5];
    float v1 = 0.f, v2 = 0.f;
#pragma unroll
    for (int it = 0; it < 5; ++it) {
        int e = e_base + it * 256 + tid;
        float y = 0.f;
        if (e < e_end) {
            int h = e / HP, w = e % HP;
            const float* p = sbase + h * SSTR + w + 1;
            float acc = cb;
#pragma unroll
            for (int u = 0; u < 6; ++u)
#pragma unroll
                for (int v = 0; v < 6; ++v)
                    acc += W[u][v] * p[u * SSTR + v];
            y = acc;
            v1 += y; v2 += y * y;
        }
        yv[it] = y;
    }
    // block reduce (sum, sumsq)
    for (int off = 32; off > 0; off >>= 1) {
        v1 += __shfl_down(v1, off);
        v2 += __shfl_down(v2, off);
    }
    __shared__ float red[8];
    __shared__ float st[2];
    int lane = tid & 63, wid = tid >> 6;
    if (lane == 0) { red[wid] = v1; red[4 + wid] = v2; }
    __syncthreads();
    if (tid == 0) {
        ws[OFF_PART + blk * 2]     = red[0] + red[1] + red[2] + red[3];
        ws[OFF_PART + blk * 2 + 1] = red[4] + red[5] + red[6] + red[7];
    }

    grid.sync();

    // ---------------- Phase 3: stats + normalize + leaky-relu ---------------
    float s1 = 0.f, s2 = 0.f;
    if (tid < 64) {
        s1 = ws[OFF_PART + (bb * 64 + tid) * 2];
        s2 = ws[OFF_PART + (bb * 64 + tid) * 2 + 1];
    }
    if (wid == 0) {
        for (int off = 32; off > 0; off >>= 1) {
            s1 += __shfl_down(s1, off);
            s2 += __shfl_down(s2, off);
        }
        if (tid == 0) {
            float mu = s1 / (float)NPB;
            float var = s2 / (float)NPB - mu * mu;
            st[0] = mu;
            st[1] = 1.0f / sqrtf(var + 1e-5f);
        }
    }
    __syncthreads();
    const float mu = st[0], rs = st[1];
    float* ob = out + bb * NPB;
#pragma unroll
    for (int it = 0; it < 5; ++it) {
        int e = e_base + it * 256 + tid;
        if (e < e_end) {
            float z = (yv[it] - mu) * rs;
            ob[e] = (z >= 0.f) ? z : 0.01f * z;
        }
    }
}

extern "C" void kernel_launch(void* const* d_in, const int* in_sizes, int n_in,
                              void* d_out, int out_size, void* d_ws, size_t ws_size,
                              hipStream_t stream) {
    const float* x  = (const float*)d_in[0];   // [8,64,256,256]
    const float* cw = (const float*)d_in[1];   // [1,8]
    const float* cb = (const float*)d_in[2];   // [1]
    float* out = (float*)d_out;                // [8,1,257,257]
    float* ws  = (float*)d_ws;

    void* args[] = {(void*)&x, (void*)&cw, (void*)&cb, (void*)&ws, (void*)&out};
    hipLaunchCooperativeKernel((void*)k_fused, dim3(GRID), dim3(256),
                               args, 0, stream);
}

// Round 5
// 195.402 us; speedup vs baseline: 1.6283x; 1.6283x over previous
//
#include <hip/hip_runtime.h>
#include <math.h>

typedef float vfloat4 __attribute__((ext_vector_type(4)));

// Problem constants
#define BB 8
#define CC 64
#define HH 256
#define WW 256
#define HP 257                     // output spatial (H+1)
#define NPB (HP * HP)              // 66049 outputs per batch

// Padded channel-sum buffer: 262 rows (3 halo top/bottom), stride 268 floats
// (4 left-halo floats for alignment, >=3 halo + vector-load slack on right).
#define SROWS 262
#define SSTR  268
#define SPIMG (SROWS * SSTR)       // 70216 floats per image
#define SSTR4 (SSTR / 4)           // 67

// y buffer: padded row stride 260 (mult of 4) for aligned float4 access
#define YSTR 260
#define YIMG (HP * YSTR)           // 66820

// Workspace layout (floats):
#define OFF_PART 0                 // 8*66*2 = 1056 partial pairs
#define OFF_Y    2048              // 8*66820 = 534560
#define OFF_P    536608            // 2 partial planes, 2*8*65536 = 1048576
#define OFF_SPAD 1585184           // 8*70216 = 561728  (total ~8.6 MB)

// K2 sizing
#define N_INT (BB * 16384)         // interior float4 items (131072)
#define PAD_PER_IMG 1170           // 6*67 full rows + 256*3 side cols
#define N_TOT (N_INT + BB * PAD_PER_IMG)   // 140432

// K3/K4 sizing: per batch, 257 rows x 65 w-groups of 4
#define GPB (HP * 65)              // 16705 groups per batch
#define CBLK 66                    // ceil(16705/256)

// ---- K1: channel half-sum (32 ch/thread, 2 halves) into partial planes ----
__global__ __launch_bounds__(256) void k_chansum(const float* __restrict__ x,
                                                 float* __restrict__ ws) {
    int idx = blockIdx.x * 256 + threadIdx.x;   // [0, 262144)
    int half = idx >> 17;
    int r = idx & 131071;
    int b = r >> 14;                            // 16384 float4 per image
    int p = r & 16383;
    const vfloat4* xp = reinterpret_cast<const vfloat4*>(x)
                        + (size_t)b * (CC * 16384) + (size_t)half * (32 * 16384) + p;
    vfloat4 acc = {0.f, 0.f, 0.f, 0.f};
#pragma unroll 16
    for (int c = 0; c < 32; ++c) {
        vfloat4 v = __builtin_nontemporal_load(&xp[(size_t)c * 16384]);
        acc += v;
    }
    reinterpret_cast<vfloat4*>(ws + OFF_P)[half * 131072 + r] = acc;
}

// ---- K2: combine halves into padded buffer + zero halos ----
__global__ __launch_bounds__(256) void k_combine(float* __restrict__ ws) {
    int idx = blockIdx.x * 256 + threadIdx.x;
    if (idx >= N_TOT) return;
    vfloat4* sp4 = reinterpret_cast<vfloat4*>(ws + OFF_SPAD);
    if (idx < N_INT) {
        const vfloat4* p04 = reinterpret_cast<const vfloat4*>(ws + OFF_P);
        vfloat4 s = p04[idx] + p04[131072 + idx];
        int b = idx >> 14;
        int p = idx & 16383;
        int i = p >> 6, j4 = p & 63;
        sp4[b * (SPIMG / 4) + (i + 3) * SSTR4 + 1 + j4] = s;
    } else {
        int k = idx - N_INT;
        int img = k / PAD_PER_IMG;
        int k2 = k % PAD_PER_IMG;
        int row, col4;
        if (k2 < 402) {                         // 3 top + 3 bottom full rows
            int rr = k2 / 67;
            row = (rr < 3) ? rr : 256 + rr;     // 0,1,2 / 259,260,261
            col4 = k2 % 67;
        } else {                                // side pads, rows 3..258
            int k3 = k2 - 402;
            row = 3 + k3 / 3;
            int m = k3 % 3;
            col4 = (m == 0) ? 0 : 64 + m;       // 0, 65, 66
        }
        vfloat4 z = {0.f, 0.f, 0.f, 0.f};
        sp4[img * (SPIMG / 4) + row * SSTR4 + col4] = z;
    }
}

// ---- build combined 6x6 weights: (2x2 avg-pool) ∘ (16-tap 5x5 shift stencil) ----
__device__ __forceinline__ void build_w(const float* __restrict__ cw, float W[6][6]) {
    float T[5][5];
#pragma unroll
    for (int i = 0; i < 5; ++i)
#pragma unroll
        for (int j = 0; j < 5; ++j) T[i][j] = 0.f;
#pragma unroll
    for (int d = 0; d < 5; ++d) { T[0][d] = -cw[d]; T[4][d] = cw[4 - d]; }
    T[1][4] = -cw[5]; T[2][4] = -cw[6]; T[3][4] = -cw[7];
    T[1][0] =  cw[7]; T[2][0] =  cw[6]; T[3][0] =  cw[5];
#pragma unroll
    for (int u = 0; u < 6; ++u)
#pragma unroll
        for (int v = 0; v < 6; ++v) {
            float a = 0.f;
#pragma unroll
            for (int dr = u - 1; dr <= u; ++dr)
#pragma unroll
                for (int dc = v - 1; dc <= v; ++dc)
                    if (dr >= 0 && dr < 5 && dc >= 0 && dc < 5) a += T[dr][dc];
            W[u][v] = 0.25f * a;
        }
}

// ---- K3: 6x6 stencil, 4 outputs/thread via float4 row loads; y + partials ----
__global__ __launch_bounds__(256) void k_conv(float* __restrict__ ws,
                                              const float* __restrict__ cw,
                                              const float* __restrict__ cbp) {
    int b = blockIdx.y;
    int g = blockIdx.x * 256 + threadIdx.x;
    float v1 = 0.f, v2 = 0.f;
    if (g < GPB) {
        float W[6][6];
        build_w(cw, W);
        const float cb = cbp[0];
        int h = g / 65, wg = g % 65, w0 = wg * 4;
        const float* sb = ws + OFF_SPAD + b * SPIMG + h * SSTR + w0;
        float acc[4] = {cb, cb, cb, cb};
#pragma unroll
        for (int u = 0; u < 6; ++u) {
            const vfloat4* rp = reinterpret_cast<const vfloat4*>(sb + u * SSTR);
            vfloat4 A = rp[0], Bv = rp[1], Cv = rp[2];
            float r[12] = {A.x, A.y, A.z, A.w, Bv.x, Bv.y, Bv.z, Bv.w,
                           Cv.x, Cv.y, Cv.z, Cv.w};
#pragma unroll
            for (int j = 0; j < 4; ++j)
#pragma unroll
                for (int v = 0; v < 6; ++v)
                    acc[j] += W[u][v] * r[1 + j + v];
        }
        vfloat4 yo = {acc[0], acc[1], acc[2], acc[3]};
        reinterpret_cast<vfloat4*>(ws + OFF_Y + b * YIMG + h * YSTR + w0)[0] = yo;
        int nv = (wg == 64) ? 1 : 4;
#pragma unroll
        for (int j = 0; j < 4; ++j)
            if (j < nv) { v1 += acc[j]; v2 += acc[j] * acc[j]; }
    }
    // block reduce (sum, sumsq)
    for (int off = 32; off > 0; off >>= 1) {
        v1 += __shfl_down(v1, off);
        v2 += __shfl_down(v2, off);
    }
    __shared__ float red[8];
    int lane = threadIdx.x & 63, wid = threadIdx.x >> 6;
    if (lane == 0) { red[wid] = v1; red[4 + wid] = v2; }
    __syncthreads();
    if (threadIdx.x == 0) {
        int pb = b * CBLK + blockIdx.x;
        ws[OFF_PART + 2 * pb]     = red[0] + red[1] + red[2] + red[3];
        ws[OFF_PART + 2 * pb + 1] = red[4] + red[5] + red[6] + red[7];
    }
}

// ---- K4: per-block stats reduce + normalize + leaky-relu ----
__global__ __launch_bounds__(256) void k_final(const float* __restrict__ ws,
                                               float* __restrict__ out) {
    int b = blockIdx.y;
    int tid = threadIdx.x;
    float v1 = 0.f, v2 = 0.f;
    if (tid < CBLK) {
        v1 = ws[OFF_PART + 2 * (b * CBLK + tid)];
        v2 = ws[OFF_PART + 2 * (b * CBLK + tid) + 1];
    }
    for (int off = 32; off > 0; off >>= 1) {
        v1 += __shfl_down(v1, off);
        v2 += __shfl_down(v2, off);
    }
    __shared__ float red[8];
    __shared__ float st[2];
    int lane = tid & 63, wid = tid >> 6;
    if (lane == 0) { red[wid] = v1; red[4 + wid] = v2; }
    __syncthreads();
    if (tid == 0) {
        float s1 = red[0] + red[1] + red[2] + red[3];
        float s2 = red[4] + red[5] + red[6] + red[7];
        float mu = s1 / (float)NPB;
        float var = s2 / (float)NPB - mu * mu;
        st[0] = mu;
        st[1] = 1.0f / sqrtf(var + 1e-5f);
    }
    __syncthreads();
    const float mu = st[0], rs = st[1];
    int g = blockIdx.x * 256 + tid;
    if (g < GPB) {
        int h = g / 65, wg = g % 65, w0 = wg * 4;
        vfloat4 yv = reinterpret_cast<const vfloat4*>(ws + OFF_Y + b * YIMG
                                                      + h * YSTR + w0)[0];
        float yr[4] = {yv.x, yv.y, yv.z, yv.w};
        int nv = (wg == 64) ? 1 : 4;
        float* ob = out + b * NPB + h * HP + w0;
#pragma unroll
        for (int j = 0; j < 4; ++j)
            if (j < nv) {
                float z = (yr[j] - mu) * rs;
                ob[j] = (z >= 0.f) ? z : 0.01f * z;
            }
    }
}

extern "C" void kernel_launch(void* const* d_in, const int* in_sizes, int n_in,
                              void* d_out, int out_size, void* d_ws, size_t ws_size,
                              hipStream_t stream) {
    const float* x  = (const float*)d_in[0];   // [8,64,256,256]
    const float* cw = (const float*)d_in[1];   // [1,8]
    const float* cb = (const float*)d_in[2];   // [1]
    float* out = (float*)d_out;                // [8,1,257,257]
    float* ws  = (float*)d_ws;

    k_chansum<<<1024, 256, 0, stream>>>(x, ws);
    k_combine<<<(N_TOT + 255) / 256, 256, 0, stream>>>(ws);
    dim3 g(CBLK, BB);
    k_conv<<<g, 256, 0, stream>>>(ws, cw, cb);
    k_final<<<g, 256, 0, stream>>>(ws, out);
}

// Round 6
// 190.667 us; speedup vs baseline: 1.6687x; 1.0248x over previous
//
#include <hip/hip_runtime.h>
#include <math.h>

typedef float vfloat4 __attribute__((ext_vector_type(4)));

// Problem constants
#define BB 8
#define CC 64
#define HH 256
#define WW 256
#define HP 257                     // output spatial (H+1)
#define NPB (HP * HP)              // 66049 outputs per batch

// Padded channel-sum buffer: 262 rows (3 halo top/bottom), stride 268 floats
// (4 left-halo floats for alignment, >=3 halo + vector-load slack on right).
#define SROWS 262
#define SSTR  268
#define SPIMG (SROWS * SSTR)       // 70216 floats per image
#define SSTR4 (SSTR / 4)           // 67

// y buffer: padded row stride 260 (mult of 4) for aligned float4 access
#define YSTR 260
#define YIMG (HP * YSTR)           // 66820

// Workspace layout (floats):
#define OFF_PART 0                 // 8*66*2 = 1056 partial pairs
#define OFF_Y    2048              // 8*66820 = 534560
#define OFF_SPAD 536608            // 8*70216 = 561728 (total ~4.4 MB)

// K1 sizing: 2048 row-blocks (8 img x 256 rows) + 37 pad blocks
#define CHBLKS 2048
#define PAD_PER_IMG 1170           // 6*67 full rows + 256*3 side cols
#define NPAD (BB * PAD_PER_IMG)    // 9360
#define PADBLKS ((NPAD + 255) / 256)   // 37

// K3/K4 sizing: per batch, 257 rows x 65 w-groups of 4
#define GPB (HP * 65)              // 16705 groups per batch
#define CBLK 66                    // ceil(16705/256)

// ---- K1: channel sum (4 groups x 16 ch, LDS reduce) into padded buffer ----
__global__ __launch_bounds__(256) void k_chansum(const float* __restrict__ x,
                                                 float* __restrict__ ws) {
    int blk = blockIdx.x;
    int t = threadIdx.x;
    vfloat4* sp4 = reinterpret_cast<vfloat4*>(ws + OFF_SPAD);
    if (blk < CHBLKS) {
        int img = blk >> 8;                 // 256 row-blocks per image
        int row = blk & 255;
        int p = t & 63;                     // float4 col within row
        int cg = t >> 6;                    // channel group 0..3
        const vfloat4* xp = reinterpret_cast<const vfloat4*>(x)
                            + (size_t)img * (CC * 16384)
                            + (size_t)(cg * 16) * 16384 + row * 64 + p;
        vfloat4 acc = {0.f, 0.f, 0.f, 0.f};
#pragma unroll
        for (int c = 0; c < 16; ++c)
            acc += __builtin_nontemporal_load(&xp[(size_t)c * 16384]);
        __shared__ vfloat4 lds[256];
        lds[t] = acc;
        __syncthreads();
        if (t < 64) {
            vfloat4 s = lds[t] + lds[t + 64] + lds[t + 128] + lds[t + 192];
            sp4[img * (SPIMG / 4) + (row + 3) * SSTR4 + 1 + t] = s;
        }
    } else {
        int k = (blk - CHBLKS) * 256 + t;
        if (k < NPAD) {
            int img = k / PAD_PER_IMG;
            int k2 = k % PAD_PER_IMG;
            int row, col4;
            if (k2 < 402) {                 // 3 top + 3 bottom full rows
                int rr = k2 / 67;
                row = (rr < 3) ? rr : 256 + rr;   // 0,1,2 / 259,260,261
                col4 = k2 % 67;
            } else {                        // side pads, rows 3..258
                int k3 = k2 - 402;
                row = 3 + k3 / 3;
                int m = k3 % 3;
                col4 = (m == 0) ? 0 : 64 + m;     // 0, 65, 66
            }
            vfloat4 z = {0.f, 0.f, 0.f, 0.f};
            sp4[img * (SPIMG / 4) + row * SSTR4 + col4] = z;
        }
    }
}

// ---- build combined 6x6 weights: (2x2 avg-pool) ∘ (16-tap 5x5 shift stencil) ----
__device__ __forceinline__ void build_w(const float* __restrict__ cw, float W[6][6]) {
    float T[5][5];
#pragma unroll
    for (int i = 0; i < 5; ++i)
#pragma unroll
        for (int j = 0; j < 5; ++j) T[i][j] = 0.f;
#pragma unroll
    for (int d = 0; d < 5; ++d) { T[0][d] = -cw[d]; T[4][d] = cw[4 - d]; }
    T[1][4] = -cw[5]; T[2][4] = -cw[6]; T[3][4] = -cw[7];
    T[1][0] =  cw[7]; T[2][0] =  cw[6]; T[3][0] =  cw[5];
#pragma unroll
    for (int u = 0; u < 6; ++u)
#pragma unroll
        for (int v = 0; v < 6; ++v) {
            float a = 0.f;
#pragma unroll
            for (int dr = u - 1; dr <= u; ++dr)
#pragma unroll
                for (int dc = v - 1; dc <= v; ++dc)
                    if (dr >= 0 && dr < 5 && dc >= 0 && dc < 5) a += T[dr][dc];
            W[u][v] = 0.25f * a;
        }
}

// ---- K3: 6x6 stencil, 4 outputs/thread via float4 row loads; y + partials ----
__global__ __launch_bounds__(256) void k_conv(float* __restrict__ ws,
                                              const float* __restrict__ cw,
                                              const float* __restrict__ cbp) {
    int b = blockIdx.y;
    int g = blockIdx.x * 256 + threadIdx.x;
    float v1 = 0.f, v2 = 0.f;
    if (g < GPB) {
        float W[6][6];
        build_w(cw, W);
        const float cb = cbp[0];
        int h = g / 65, wg = g % 65, w0 = wg * 4;
        const float* sb = ws + OFF_SPAD + b * SPIMG + h * SSTR + w0;
        float acc[4] = {cb, cb, cb, cb};
#pragma unroll
        for (int u = 0; u < 6; ++u) {
            const vfloat4* rp = reinterpret_cast<const vfloat4*>(sb + u * SSTR);
            vfloat4 A = rp[0], Bv = rp[1], Cv = rp[2];
            float r[12] = {A.x, A.y, A.z, A.w, Bv.x, Bv.y, Bv.z, Bv.w,
                           Cv.x, Cv.y, Cv.z, Cv.w};
#pragma unroll
            for (int j = 0; j < 4; ++j)
#pragma unroll
                for (int v = 0; v < 6; ++v)
                    acc[j] += W[u][v] * r[1 + j + v];
        }
        vfloat4 yo = {acc[0], acc[1], acc[2], acc[3]};
        reinterpret_cast<vfloat4*>(ws + OFF_Y + b * YIMG + h * YSTR + w0)[0] = yo;
        int nv = (wg == 64) ? 1 : 4;
#pragma unroll
        for (int j = 0; j < 4; ++j)
            if (j < nv) { v1 += acc[j]; v2 += acc[j] * acc[j]; }
    }
    // block reduce (sum, sumsq)
    for (int off = 32; off > 0; off >>= 1) {
        v1 += __shfl_down(v1, off);
        v2 += __shfl_down(v2, off);
    }
    __shared__ float red[8];
    int lane = threadIdx.x & 63, wid = threadIdx.x >> 6;
    if (lane == 0) { red[wid] = v1; red[4 + wid] = v2; }
    __syncthreads();
    if (threadIdx.x == 0) {
        int pb = b * CBLK + blockIdx.x;
        ws[OFF_PART + 2 * pb]     = red[0] + red[1] + red[2] + red[3];
        ws[OFF_PART + 2 * pb + 1] = red[4] + red[5] + red[6] + red[7];
    }
}

// ---- K4: per-block stats reduce + normalize + leaky-relu ----
__global__ __launch_bounds__(256) void k_final(const float* __restrict__ ws,
                                               float* __restrict__ out) {
    int b = blockIdx.y;
    int tid = threadIdx.x;
    float v1 = 0.f, v2 = 0.f;
    if (tid < CBLK) {
        v1 = ws[OFF_PART + 2 * (b * CBLK + tid)];
        v2 = ws[OFF_PART + 2 * (b * CBLK + tid) + 1];
    }
    for (int off = 32; off > 0; off >>= 1) {
        v1 += __shfl_down(v1, off);
        v2 += __shfl_down(v2, off);
    }
    __shared__ float red[8];
    __shared__ float st[2];
    int lane = tid & 63, wid = tid >> 6;
    if (lane == 0) { red[wid] = v1; red[4 + wid] = v2; }
    __syncthreads();
    if (tid == 0) {
        float s1 = red[0] + red[1] + red[2] + red[3];
        float s2 = red[4] + red[5] + red[6] + red[7];
        float mu = s1 / (float)NPB;
        float var = s2 / (float)NPB - mu * mu;
        st[0] = mu;
        st[1] = 1.0f / sqrtf(var + 1e-5f);
    }
    __syncthreads();
    const float mu = st[0], rs = st[1];
    int g = blockIdx.x * 256 + tid;
    if (g < GPB) {
        int h = g / 65, wg = g % 65, w0 = wg * 4;
        vfloat4 yv = reinterpret_cast<const vfloat4*>(ws + OFF_Y + b * YIMG
                                                      + h * YSTR + w0)[0];
        float yr[4] = {yv.x, yv.y, yv.z, yv.w};
        int nv = (wg == 64) ? 1 : 4;
        float* ob = out + b * NPB + h * HP + w0;
#pragma unroll
        for (int j = 0; j < 4; ++j)
            if (j < nv) {
                float z = (yr[j] - mu) * rs;
                ob[j] = (z >= 0.f) ? z : 0.01f * z;
            }
    }
}

extern "C" void kernel_launch(void* const* d_in, const int* in_sizes, int n_in,
                              void* d_out, int out_size, void* d_ws, size_t ws_size,
                              hipStream_t stream) {
    const float* x  = (const float*)d_in[0];   // [8,64,256,256]
    const float* cw = (const float*)d_in[1];   // [1,8]
    const float* cb = (const float*)d_in[2];   // [1]
    float* out = (float*)d_out;                // [8,1,257,257]
    float* ws  = (float*)d_ws;

    k_chansum<<<CHBLKS + PADBLKS, 256, 0, stream>>>(x, ws);
    dim3 g(CBLK, BB);
    k_conv<<<g, 256, 0, stream>>>(ws, cw, cb);
    k_final<<<g, 256, 0, stream>>>(ws, out);
}